// Round 3
// baseline (17.732 us; speedup 1.0000x reference)
//
#include <hip/hip_runtime.h>
#include <hip/hip_bf16.h>

#define B_    8
#define N_    128
#define NB_   32
#define NORB_ 128
#define RPB   8      // output rows per block
#define KSPL  2      // K split across blocks (512 kl each)
#define THREADS 1024

__global__ __launch_bounds__(THREADS, 4) void bobf_kernel(
    const float* __restrict__ chi,
    const float* __restrict__ W,
    float* __restrict__ out)
{
    __shared__ float Sp[32][NB_];                 // per-group partial sums for S
    __shared__ float S[NB_];                      // S[k] = sum_j chi[b,j,k]
    __shared__ float x[RPB][NB_];                 // the 8 rows' chi values
    __shared__ __align__(16) float p[512 * RPB];  // p[klloc*8 + r]   (16 KB)
    __shared__ float red[8][RPB][NORB_];          // cross-group reduction (32 KB)

    const int t   = threadIdx.x;
    const int blk = blockIdx.x;
    const int b   = blk >> 5;                     // 32 blocks per batch
    const int ig  = (blk & 31) >> 1;              // row-group 0..15
    const int kh  = blk & 1;                      // K half
    const int i0  = ig * RPB;

    // ---- Stage 1: S[k] partial sums; load the 8 rows' x ----
    {
        const int k = t & 31;
        const int g = t >> 5;                     // 0..31, each covers 4 j's
        const float* base = chi + (b * N_) * NB_ + k;
        float s = 0.f;
        #pragma unroll
        for (int jj = 0; jj < 4; ++jj)
            s += base[(g * 4 + jj) * NB_];
        Sp[g][k] = s;
    }
    if (t < RPB * NB_) {
        const int r = t >> 5, l = t & 31;
        x[r][l] = chi[(b * N_ + i0 + r) * NB_ + l];
    }
    __syncthreads();
    if (t < NB_) {
        float s = 0.f;
        #pragma unroll
        for (int g = 0; g < 32; ++g) s += Sp[g][t];
        S[t] = s;
    }
    __syncthreads();

    // ---- Stage 2: p[klloc][r] = (S[k]-x[r][k])/127 * x[r][l], kl = kh*512+klloc ----
    const float inv = 1.0f / (float)(N_ - 1);
    #pragma unroll
    for (int e = 0; e < 4; ++e) {
        const int flat  = t + THREADS * e;        // 0..4095
        const int r     = flat & (RPB - 1);
        const int klloc = flat >> 3;
        const int kl    = kh * 512 + klloc;
        const int k     = kl >> 5, l = kl & 31;
        p[flat] = (S[k] - x[r][k]) * inv * x[r][l];
    }
    __syncthreads();

    // ---- Stage 3: contraction. thread = (group q of 64 kl, orbital o) ----
    const int q = t >> 7;                         // 0..7
    const int o = t & 127;
    const float* Wp = W + (kh * 512 + q * 64) * NORB_ + o;
    const float4* p4 = ((const float4*)p) + q * 64 * 2;
    float acc[RPB];
    #pragma unroll
    for (int r = 0; r < RPB; ++r) acc[r] = 0.f;
    #pragma unroll 4
    for (int j = 0; j < 64; ++j) {
        const float  w  = Wp[j * NORB_];
        const float4 a0 = p4[j * 2];              // rows 0..3 (broadcast read)
        const float4 a1 = p4[j * 2 + 1];          // rows 4..7
        acc[0] += a0.x * w;  acc[1] += a0.y * w;
        acc[2] += a0.z * w;  acc[3] += a0.w * w;
        acc[4] += a1.x * w;  acc[5] += a1.y * w;
        acc[6] += a1.z * w;  acc[7] += a1.w * w;
    }
    #pragma unroll
    for (int r = 0; r < RPB; ++r) red[q][r][o] = acc[r];
    __syncthreads();

    // ---- Stage 4: reduce 8 groups, atomic-accumulate the K-half partial ----
    {
        const int r = t >> 7;                     // 0..7
        float v = 0.f;
        #pragma unroll
        for (int qq = 0; qq < 8; ++qq) v += red[qq][r][o];
        atomicAdd(&out[(b * N_ + i0 + r) * NORB_ + o], v);
    }
}

extern "C" void kernel_launch(void* const* d_in, const int* in_sizes, int n_in,
                              void* d_out, int out_size, void* d_ws, size_t ws_size,
                              hipStream_t stream) {
    const float* chi = (const float*)d_in[0];
    const float* W   = (const float*)d_in[1];
    float* out = (float*)d_out;
    hipMemsetAsync(d_out, 0, (size_t)out_size * sizeof(float), stream);
    dim3 grid(B_ * (N_ / RPB) * KSPL);            // 256 blocks
    dim3 block(THREADS);
    hipLaunchKernelGGL(bobf_kernel, grid, block, 0, stream, chi, W, out);
}

// Round 4
// 11.847 us; speedup vs baseline: 1.4967x; 1.4967x over previous
//
#include <hip/hip_runtime.h>
#include <hip/hip_bf16.h>

#define B_    8
#define N_    128
#define NB_   32
#define NORB_ 128
#define RPB   4        // output rows per block
#define THREADS 1024
#define QG    32       // kl groups; 32 kl each

// p padded: dword addr of (kl, r) = kl*4 + (kl>>5)*4 + r  (16B pad per 32-kl stripe)
#define P_DW(kl) ((kl) * 4 + ((kl) >> 5) * 4)

__global__ __launch_bounds__(THREADS, 4) void bobf_kernel(
    const float* __restrict__ chi,
    const float* __restrict__ W,
    float* __restrict__ out)
{
    __shared__ float Sp[32][NB_];                  // S partial sums (4 KB)
    __shared__ float S[NB_];
    __shared__ float x[RPB][NB_];
    __shared__ __align__(16) float p[1024 * 4 + 32 * 4];   // 16.9 KB, padded
    __shared__ float red[QG][RPB][NORB_];          // 64 KB

    const int t  = threadIdx.x;
    const int b  = blockIdx.x >> 5;                // 32 blocks per batch
    const int i0 = (blockIdx.x & 31) * RPB;

    // ---- Stage 1: S[k] = sum_j chi[b,j,k]; load the 4 rows' x ----
    {
        const int k = t & 31;
        const int g = t >> 5;                      // 0..31, each covers 4 j's
        const float* base = chi + (b * N_) * NB_ + k;
        float s = 0.f;
        #pragma unroll
        for (int jj = 0; jj < 4; ++jj)
            s += base[(g * 4 + jj) * NB_];
        Sp[g][k] = s;
    }
    if (t < RPB * NB_) {
        const int r = t >> 5, l = t & 31;
        x[r][l] = chi[(b * N_ + i0 + r) * NB_ + l];
    }
    __syncthreads();
    if (t < NB_) {
        float s = 0.f;
        #pragma unroll
        for (int g = 0; g < 32; ++g) s += Sp[g][t];
        S[t] = s;
    }
    __syncthreads();

    // ---- Stage 2: p[kl][0..3] = (S[k]-x[r][k])/127 * x[r][l] ----
    {
        const float inv = 1.0f / (float)(N_ - 1);
        const int kl = t;                          // 0..1023
        const int k = kl >> 5, l = kl & 31;
        float4 v;
        v.x = (S[k] - x[0][k]) * inv * x[0][l];
        v.y = (S[k] - x[1][k]) * inv * x[1][l];
        v.z = (S[k] - x[2][k]) * inv * x[2][l];
        v.w = (S[k] - x[3][k]) * inv * x[3][l];
        *(float4*)&p[P_DW(kl)] = v;
    }
    __syncthreads();

    // ---- Stage 3: thread = (q, og): rows 0..3  x  o = og*4..og*4+3 ----
    const int q  = t >> 5;                         // 0..31, kl in [q*32, q*32+32)
    const int og = t & 31;
    const float4* p4 = ((const float4*)p) + q * 33;        // 33 float4 per stripe
    const float4* Wf = ((const float4*)(W + (q * 32) * NORB_)) + og;
    float4 a0 = {0,0,0,0}, a1 = {0,0,0,0}, a2 = {0,0,0,0}, a3 = {0,0,0,0};
    #pragma unroll 8
    for (int j = 0; j < 32; ++j) {
        const float4 pv = p4[j];                   // 4 rows (broadcast per half-wave)
        const float4 wv = Wf[j * 32];              // W[q*32+j][og*4 .. +3]
        a0.x += pv.x * wv.x; a0.y += pv.x * wv.y; a0.z += pv.x * wv.z; a0.w += pv.x * wv.w;
        a1.x += pv.y * wv.x; a1.y += pv.y * wv.y; a1.z += pv.y * wv.z; a1.w += pv.y * wv.w;
        a2.x += pv.z * wv.x; a2.y += pv.z * wv.y; a2.z += pv.z * wv.z; a2.w += pv.z * wv.w;
        a3.x += pv.w * wv.x; a3.y += pv.w * wv.y; a3.z += pv.w * wv.z; a3.w += pv.w * wv.w;
    }
    *(float4*)&red[q][0][og * 4] = a0;
    *(float4*)&red[q][1][og * 4] = a1;
    *(float4*)&red[q][2][og * 4] = a2;
    *(float4*)&red[q][3][og * 4] = a3;
    __syncthreads();

    // ---- Stage 4: reduce 32 q-groups, store ----
    if (t < RPB * NORB_) {
        const int r = t >> 7, o = t & 127;
        float v = 0.f;
        #pragma unroll
        for (int qq = 0; qq < QG; ++qq) v += red[qq][r][o];
        out[(b * N_ + i0 + r) * NORB_ + o] = v;
    }
}

extern "C" void kernel_launch(void* const* d_in, const int* in_sizes, int n_in,
                              void* d_out, int out_size, void* d_ws, size_t ws_size,
                              hipStream_t stream) {
    const float* chi = (const float*)d_in[0];
    const float* W   = (const float*)d_in[1];
    float* out = (float*)d_out;
    dim3 grid(B_ * (N_ / RPB));    // 256 blocks
    dim3 block(THREADS);
    hipLaunchKernelGGL(bobf_kernel, grid, block, 0, stream, chi, W, out);
}